// Round 1
// baseline (6831.531 us; speedup 1.0000x reference)
//
#include <hip/hip_runtime.h>
#include <stdint.h>

// Problem constants
#define NB   131072
#define DIN  128
#define HD   256
#define VT   6
#define TS   6
// Tiling: BM=64 rows/block as TWO independent 32-row half-pipelines.
// 512 threads = 8 waves; waves 0-3 = half A (rows 0-31), waves 4-7 = half B
// (rows 32-63). Half B runs one barrier-slot behind half A, so every
// __syncthreads interval pairs one half's GEMM (MFMA pipe) with the other
// half's activation/pack (VALU pipe) -> deterministic pipe overlap.
// MFMA 16x16x32 bf16; fp32 exact via 3-plane bf16 split (6 products).
#define BM   64
#define NTH  512

typedef __attribute__((ext_vector_type(8))) short bfrag;   // 8 bf16 (4 VGPRs)
typedef __attribute__((ext_vector_type(4))) short bh4;     // 4 bf16
typedef __attribute__((ext_vector_type(4))) float f32x4;   // MFMA C/D

struct Keys { uint32_t a[6]; uint32_t b[6]; };

// hp plane layout: [p][kc][nt 2][lane 64][8] shorts, +16-short pad per (p,kc) block.
#define HPS(p, kc, nt, lp, j) ((((p) * 8 + (kc)) * 1040) + (nt) * 512 + (lp) * 8 + (j))
#define HPHALF (3 * 8 * 1040)   // shorts per 32-row half = 24,960 (49,920 B)

// ---- JAX threefry2x32 (20 rounds), bit-exact ----
__host__ __device__ inline void tf2x32(uint32_t k0, uint32_t k1,
                                       uint32_t c0, uint32_t c1,
                                       uint32_t& o0, uint32_t& o1) {
  uint32_t ks2 = k0 ^ k1 ^ 0x1BD11BDAu;
  uint32_t x0 = c0 + k0, x1 = c1 + k1;
#define TFR(d) { x0 += x1; x1 = (x1 << (d)) | (x1 >> (32 - (d))); x1 ^= x0; }
  TFR(13) TFR(15) TFR(26) TFR(6)
  x0 += k1;  x1 += ks2 + 1u;
  TFR(17) TFR(29) TFR(16) TFR(24)
  x0 += ks2; x1 += k0 + 2u;
  TFR(13) TFR(15) TFR(26) TFR(6)
  x0 += k0;  x1 += k1 + 3u;
  TFR(17) TFR(29) TFR(16) TFR(24)
  x0 += k1;  x1 += ks2 + 4u;
  TFR(13) TFR(15) TFR(26) TFR(6)
  x0 += ks2; x1 += k0 + 5u;
#undef TFR
  o0 = x0; o1 = x1;
}

__device__ __forceinline__ unsigned short f2bf(float x) {   // RNE f32->bf16
  uint32_t b = __float_as_uint(x);
  uint32_t r = b + 0x7FFFu + ((b >> 16) & 1u);
  return (unsigned short)(r >> 16);
}
__device__ __forceinline__ float bf2f(unsigned short u) {
  return __uint_as_float(((uint32_t)u) << 16);
}
__device__ __forceinline__ float sigf(float v) { return 1.0f / (1.0f + expf(-v)); }

#define MFMA16(a, b, c) __builtin_amdgcn_mfma_f32_16x16x32_bf16((a), (b), (c), 0, 0, 0)

// 6-product bf16x3: (hi,hi),(hi,mid),(mid,hi),(mid,mid),(hi,lo),(lo,hi)
__device__ __forceinline__ f32x4 prod6(const bfrag A[3], bfrag B0, bfrag B1, bfrag B2,
                                       f32x4 c) {
  c = MFMA16(A[0], B0, c);
  c = MFMA16(A[0], B1, c);
  c = MFMA16(A[1], B0, c);
  c = MFMA16(A[1], B1, c);
  c = MFMA16(A[0], B2, c);
  c = MFMA16(A[2], B0, c);
  return c;
}

// ---- Kernel A: pre tables (gate bias folded), W frags, W_out frags ----
// A-layout: ((p*KC + kc)*16 + mt)*512 + lane*8 + j holds
// A[m = mt*16 + (lane&15)][k = kc*32 + (lane>>4)*8 + j] = W[krow0+k][m].
__global__ void pre_kernel(const float* __restrict__ W_enc,
                           const float* __restrict__ W_embed,
                           const float* __restrict__ b_embed,
                           const float* __restrict__ start_embed,
                           const float* __restrict__ W_z, const float* __restrict__ b_z,
                           const float* __restrict__ W_r, const float* __restrict__ b_r,
                           const float* __restrict__ W_h, const float* __restrict__ b_h,
                           const float* __restrict__ W_out,
                           float* __restrict__ pre,
                           unsigned short* __restrict__ encf,
                           unsigned short* __restrict__ zf,
                           unsigned short* __restrict__ rf,
                           unsigned short* __restrict__ hf,
                           unsigned short* __restrict__ woutf) {
  const int bid = blockIdx.x;
  if (bid < 24) {  // pre tables: codes 0..5 = W_embed[c]+b_embed, 6 = b_embed, 7 = start
    __shared__ float xin[HD];
    const int c = bid & 7, g = bid >> 3, j = threadIdx.x;
    float v;
    if (c < 6)       v = W_embed[c * HD + j] + b_embed[j];
    else if (c == 6) v = b_embed[j];
    else             v = start_embed[j];
    xin[j] = v;
    __syncthreads();
    const float* Wg = (g == 0) ? W_z : (g == 1) ? W_r : W_h;  // top half rows 0..255
    const float* bg = (g == 0) ? b_z : (g == 1) ? b_r : b_h;
    float acc = bg[j];                       // fold gate bias into pre table
    for (int k = 0; k < HD; ++k) acc += xin[k] * Wg[k * HD + j];
    pre[(g * 8 + c) * HD + j] = acc;
    return;
  }
  if (bid >= 136) {  // W_out frags: single mt, KC=8; A[m][k] = W_out[k][m] (m<6)
    int id2 = (bid - 136) * 256 + threadIdx.x;   // 0..511
    int kc = id2 >> 6, lane = id2 & 63;
    int m = lane & 15, k0 = kc * 32 + ((lane >> 4) & 3) * 8;
    __align__(16) unsigned short P[3][8];
#pragma unroll
    for (int j = 0; j < 8; ++j) {
      float w = (m < VT) ? W_out[(size_t)(k0 + j) * VT + m] : 0.f;
      unsigned short h1 = f2bf(w);  float r1 = w - bf2f(h1);
      unsigned short h2 = f2bf(r1); float r2 = r1 - bf2f(h2);
      P[0][j] = h1; P[1][j] = h2; P[2][j] = f2bf(r2);
    }
    for (int p = 0; p < 3; ++p) {
      unsigned short* d = woutf + ((size_t)(p * 8 + kc) * 512) + (size_t)lane * 8;
      *(uint4*)d = *(const uint4*)P[p];
    }
    return;
  }
  int id = (bid - 24) * 256 + threadIdx.x;   // 0 .. 28671
  const float* src; unsigned short* dst; int kc, mt, lane, KC, krow0;
  if (id < 4096) {            // encoder frags: KC=4 (K=128)
    lane = id & 63; mt = (id >> 6) & 15; kc = id >> 10;
    src = W_enc; dst = encf; KC = 4; krow0 = 0;
  } else {                    // gate frags: KC=8 (K=256), bottom half rows 256..511
    int rem = id - 4096; int g = rem >> 13; int rr = rem & 8191;
    lane = rr & 63; mt = (rr >> 6) & 15; kc = rr >> 10;
    src = (g == 0) ? W_z : (g == 1) ? W_r : W_h;
    dst = (g == 0) ? zf  : (g == 1) ? rf  : hf;
    KC = 8; krow0 = 256;
  }
  const int m  = mt * 16 + (lane & 15);
  const int k0 = kc * 32 + ((lane >> 4) & 3) * 8;
  __align__(16) unsigned short P[3][8];
#pragma unroll
  for (int j = 0; j < 8; ++j) {
    float w = src[(size_t)(krow0 + k0 + j) * HD + m];
    unsigned short h1 = f2bf(w);  float r1 = w - bf2f(h1);
    unsigned short h2 = f2bf(r1); float r2 = r1 - bf2f(h2);
    P[0][j] = h1; P[1][j] = h2; P[2][j] = f2bf(r2);   // hi+mid+lo == w exactly
  }
  for (int p = 0; p < 3; ++p) {
    unsigned short* d = dst + ((size_t)(p * KC + kc) * 16 + mt) * 512 + (size_t)lane * 8;
    *(uint4*)d = *(const uint4*)P[p];
  }
}

// GEMM pass: A = W frags (global/L2), B = h planes (LDS, conflict-free).
// Wave owns mt = w4*4 + mtl. NG=2 shares B across two A streams (z+r fused).
template<int KC, int NG>
__device__ __forceinline__ void gemm_pass(const unsigned short* __restrict__ f0,
                                          const unsigned short* __restrict__ f1,
                                          const unsigned short* hp,
                                          int w4, int lane,
                                          f32x4 acc0[4][2], f32x4 acc1[4][2]) {
#pragma unroll 1
  for (int kc = 0; kc < KC; ++kc) {
    bfrag B[3][2];
#pragma unroll
    for (int p = 0; p < 3; ++p)
#pragma unroll
      for (int nt = 0; nt < 2; ++nt)
        B[p][nt] = *(const bfrag*)&hp[HPS(p, kc, nt, lane, 0)];
#pragma unroll
    for (int mtl = 0; mtl < 4; ++mtl) {
      const int fo = (kc * 16 + w4 * 4 + mtl) * 512 + lane * 8;
      bfrag A0[3], A1[3];
#pragma unroll
      for (int p = 0; p < 3; ++p) A0[p] = *(const bfrag*)(f0 + fo + p * (KC * 8192));
      if (NG == 2) {
#pragma unroll
        for (int p = 0; p < 3; ++p) A1[p] = *(const bfrag*)(f1 + fo + p * (KC * 8192));
      }
#pragma unroll
      for (int nt = 0; nt < 2; ++nt) {
        acc0[mtl][nt] = prod6(A0, B[0][nt], B[1][nt], B[2][nt], acc0[mtl][nt]);
        if (NG == 2)
          acc1[mtl][nt] = prod6(A1, B[0][nt], B[1][nt], B[2][nt], acc1[mtl][nt]);
      }
    }
  }
}

// gumbel batch for step s, tile (16 rows), into double-buffered LDS (per half)
__device__ __forceinline__ void gen_gumbel(float* __restrict__ gmb, int s, int b0,
                                           int tile, int lane,
                                           uint32_t ka, uint32_t kb) {
  uint32_t basej = (uint32_t)(b0 + tile * 16) * 6u;
#pragma unroll
  for (int rep = 0; rep < 2; ++rep) {
    int d = rep * 64 + lane;
    if (d < 96) {
      uint32_t o0, o1;
      tf2x32(ka, kb, 0u, basej + (uint32_t)d, o0, o1);
      uint32_t bits = o0 ^ o1;
      float f = __uint_as_float((bits >> 9) | 0x3f800000u) - 1.0f;
      float u = (f > 0.f) ? f : 1.175494350822288e-38f;
      float lg1 = (float)log((double)u);
      float lg2 = (float)log((double)(-lg1));
      gmb[((s & 1) * 32 + tile * 16 + d / 6) * 6 + (d % 6)] = -lg2;
    }
  }
}

// ---- main kernel: persistent rollout; h_old in registers; logits via MFMA.
// Two independent 32-row half-pipelines per block, phase-skewed by one
// barrier slot: each __syncthreads interval pairs half-X's GEMM (MFMA) with
// half-Y's activation/pack (VALU). Each SIMD holds exactly one wave of each
// half -> both pipes stay fed. Per-row math is bit-identical to the BM=32
// version (rows merely re-grouped), so outputs are unchanged.
__launch_bounds__(NTH, 2)
__global__ void main_kernel(const float* __restrict__ x,
                            const float* __restrict__ b_enc,
                            const float* __restrict__ b_out,
                            const float* __restrict__ pre,
                            const unsigned short* __restrict__ encf,
                            const unsigned short* __restrict__ zf,
                            const unsigned short* __restrict__ rf,
                            const unsigned short* __restrict__ hf,
                            const unsigned short* __restrict__ woutf,
                            float* __restrict__ out, Keys keys) {
  __shared__ __align__(16) unsigned short hp_s[2 * HPHALF];    // 99,840 B
  __shared__ float gmb_s[2 * 2 * 32 * 6];                      //  3,072 B
  __shared__ float boutL[16];
  __shared__ unsigned state_s[2 * 32];
  __shared__ float tlp_s[2 * 32];
  // total ~103.5 KB -> 1 block/CU (8 waves; by design: overlap is in-block)

  const int tid  = threadIdx.x;
  const int wave = tid >> 6, lane = tid & 63;
  const int grp  = wave >> 2;          // 0 = half A, 1 = half B
  const int w4   = wave & 3;           // wave-in-half
  const int ln   = lane & 15, qk = lane >> 4;
  const int tid4 = tid & 255;          // thread-in-half
  const int b0   = blockIdx.x * BM + grp * 32;

  unsigned short* hp   = hp_s    + grp * HPHALF;
  float*          gmb  = gmb_s   + grp * (2 * 32 * 6);
  unsigned*       stp  = state_s + grp * 32;
  float*          tlpp = tlp_s   + grp * 32;

  f32x4 acc0[4][2], acc1[4][2], z_s[4][2], hold[4][2];

  // Phase schedule per half (34 phases):
  //   0: STAGE   1: G_ENC   2: P_ENC
  //   3+5t+0: G_ZR  +1: P_RH  +2: G_H  +3: P_H  +4: L (logits/sample || gumbel)
  //   33: EPI
  // Half B executes phase (slot-1): one-slot skew -> anti-phased pipes.
#pragma unroll 1
  for (int slot = 0; slot < 35; ++slot) {
    const int ph = slot - grp;
    if (ph == 0) {
      // ---- STAGE: x -> B-operand planes for this half's 32 rows ----
      if (tid4 < 16) boutL[tid4] = (tid4 < VT) ? b_out[tid4] : 0.f;
      if (tid4 < 32) { stp[tid4] = 7u; tlpp[tid4] = 0.f; }
      for (int i = tid4; i < 32 * DIN; i += 256) {
        int row = i >> 7, k = i & 127;
        float v = x[(size_t)(b0 + row) * DIN + k];
        unsigned short h1 = f2bf(v);  float r1 = v - bf2f(h1);
        unsigned short h2 = f2bf(r1); float r2 = r1 - bf2f(h2);
        int kc = k >> 5, nt = row >> 4, lp = (row & 15) + 16 * ((k >> 3) & 3), j = k & 7;
        hp[HPS(0, kc, nt, lp, j)] = h1;
        hp[HPS(1, kc, nt, lp, j)] = h2;
        hp[HPS(2, kc, nt, lp, j)] = f2bf(r2);
      }
      // waves 2-3 of the half: step-0 gumbels
      if (w4 >= 2) gen_gumbel(gmb, 0, b0, w4 - 2, lane, keys.a[0], keys.b[0]);
    } else if (ph == 1) {
      // ---- G_ENC: h0 = x @ W_enc + b_enc ----
#pragma unroll
      for (int mtl = 0; mtl < 4; ++mtl) {
        int mb = (w4 * 4 + mtl) * 16 + qk * 4;
        f32x4 be = *(const f32x4*)&b_enc[mb];
#pragma unroll
        for (int nt = 0; nt < 2; ++nt) acc0[mtl][nt] = be;
      }
      gemm_pass<4, 1>(encf, nullptr, hp, w4, lane, acc0, acc1);
    } else if (ph == 2) {
      // ---- P_ENC: split h0, publish planes; h_old lives in registers ----
#pragma unroll
      for (int mtl = 0; mtl < 4; ++mtl) {
        int mb = (w4 * 4 + mtl) * 16 + qk * 4;
        int kc = mb >> 5, hi2 = (mb >> 3) & 3, j0 = mb & 7, lp = ln + 16 * hi2;
#pragma unroll
        for (int nt = 0; nt < 2; ++nt) {
          f32x4 o = acc0[mtl][nt];
          hold[mtl][nt] = o;
          bh4 P0, P1, P2;
#pragma unroll
          for (int j = 0; j < 4; ++j) {
            float v = o[j];
            unsigned short h1 = f2bf(v);  float r1 = v - bf2f(h1);
            unsigned short h2 = f2bf(r1); float r2 = r1 - bf2f(h2);
            P0[j] = (short)h1; P1[j] = (short)h2; P2[j] = (short)f2bf(r2);
          }
          *(bh4*)&hp[HPS(0, kc, nt, lp, j0)] = P0;
          *(bh4*)&hp[HPS(1, kc, nt, lp, j0)] = P1;
          *(bh4*)&hp[HPS(2, kc, nt, lp, j0)] = P2;
        }
      }
    } else if (ph >= 3 && ph <= 32) {
      const int q = ph - 3;
      const int t = q / 5;
      const int sub = q - t * 5;
      if (sub == 0) {
        // ---- G_ZR: fused z+r (C-init from pre tables incl. bias) ----
#pragma unroll
        for (int mtl = 0; mtl < 4; ++mtl) {
          int mb = (w4 * 4 + mtl) * 16 + qk * 4;
#pragma unroll
          for (int nt = 0; nt < 2; ++nt) {
            int code = (int)(stp[nt * 16 + ln] & 7u);
            acc0[mtl][nt] = *(const f32x4*)&pre[(0 * 8 + code) * 256 + mb];
            acc1[mtl][nt] = *(const f32x4*)&pre[(1 * 8 + code) * 256 + mb];
          }
        }
        gemm_pass<8, 2>(zf, rf, hp, w4, lane, acc0, acc1);
      } else if (sub == 1) {
        // ---- P_RH: z = sig(.), rh = sig(.)*h_old; split & publish rh ----
#pragma unroll
        for (int mtl = 0; mtl < 4; ++mtl) {
          int mb = (w4 * 4 + mtl) * 16 + qk * 4;
          int kc = mb >> 5, hi2 = (mb >> 3) & 3, j0 = mb & 7, lp = ln + 16 * hi2;
#pragma unroll
          for (int nt = 0; nt < 2; ++nt) {
            f32x4 ho = hold[mtl][nt];
            f32x4 zv;
            bh4 P0, P1, P2;
#pragma unroll
            for (int j = 0; j < 4; ++j) {
              zv[j] = sigf(acc0[mtl][nt][j]);
              float rhv = sigf(acc1[mtl][nt][j]) * ho[j];
              unsigned short h1 = f2bf(rhv); float r1 = rhv - bf2f(h1);
              unsigned short h2 = f2bf(r1);  float r2 = r1 - bf2f(h2);
              P0[j] = (short)h1; P1[j] = (short)h2; P2[j] = (short)f2bf(r2);
            }
            z_s[mtl][nt] = zv;
            *(bh4*)&hp[HPS(0, kc, nt, lp, j0)] = P0;
            *(bh4*)&hp[HPS(1, kc, nt, lp, j0)] = P1;
            *(bh4*)&hp[HPS(2, kc, nt, lp, j0)] = P2;
          }
        }
      } else if (sub == 2) {
        // ---- G_H: candidate gate ----
#pragma unroll
        for (int mtl = 0; mtl < 4; ++mtl) {
          int mb = (w4 * 4 + mtl) * 16 + qk * 4;
#pragma unroll
          for (int nt = 0; nt < 2; ++nt) {
            int code = (int)(stp[nt * 16 + ln] & 7u);
            acc0[mtl][nt] = *(const f32x4*)&pre[(2 * 8 + code) * 256 + mb];
          }
        }
        gemm_pass<8, 1>(hf, nullptr, hp, w4, lane, acc0, acc1);
      } else if (sub == 3) {
        // ---- P_H: h_new = (1-z)h + z tanh(.); split & publish ----
#pragma unroll
        for (int mtl = 0; mtl < 4; ++mtl) {
          int mb = (w4 * 4 + mtl) * 16 + qk * 4;
          int kc = mb >> 5, hi2 = (mb >> 3) & 3, j0 = mb & 7, lp = ln + 16 * hi2;
#pragma unroll
          for (int nt = 0; nt < 2; ++nt) {
            f32x4 z = z_s[mtl][nt], ho = hold[mtl][nt], hn;
            bh4 P0, P1, P2;
#pragma unroll
            for (int j = 0; j < 4; ++j) {
              float ht = tanhf(acc0[mtl][nt][j]);
              hn[j] = (1.0f - z[j]) * ho[j] + z[j] * ht;
              unsigned short h1 = f2bf(hn[j]); float r1 = hn[j] - bf2f(h1);
              unsigned short h2 = f2bf(r1);    float r2 = r1 - bf2f(h2);
              P0[j] = (short)h1; P1[j] = (short)h2; P2[j] = (short)f2bf(r2);
            }
            hold[mtl][nt] = hn;              // persists to next step
            *(bh4*)&hp[HPS(0, kc, nt, lp, j0)] = P0;
            *(bh4*)&hp[HPS(1, kc, nt, lp, j0)] = P1;
            *(bh4*)&hp[HPS(2, kc, nt, lp, j0)] = P2;
          }
        }
      } else {
        // ---- L: logits GEMM + sample (waves 0-1) || gumbel t+1 (waves 2-3) ----
        if (w4 < 2) {
          f32x4 lacc;
#pragma unroll
          for (int j = 0; j < 4; ++j) lacc[j] = boutL[qk * 4 + j];
#pragma unroll 1
          for (int kc = 0; kc < 8; ++kc) {
            bfrag B0 = *(const bfrag*)&hp[HPS(0, kc, w4, lane, 0)];
            bfrag B1 = *(const bfrag*)&hp[HPS(1, kc, w4, lane, 0)];
            bfrag B2 = *(const bfrag*)&hp[HPS(2, kc, w4, lane, 0)];
            bfrag A[3];
#pragma unroll
            for (int p = 0; p < 3; ++p)
              A[p] = *(const bfrag*)(woutf + (p * 8 + kc) * 512 + lane * 8);
            lacc = prod6(A, B0, B1, B2, lacc);
          }
          // D[m=qk*4+j][n=ln]: vocab 0..3 at qk=0, vocab 4..5 at qk=1 regs 0..1
          float l4 = __shfl(lacc[0], ln + 16, 64);
          float l5 = __shfl(lacc[1], ln + 16, 64);
          if (qk == 0) {
            const int m = w4 * 16 + ln;
            const int row = b0 + m;
            unsigned st = stp[m];
            if (!(st & 8u)) {
              float l[VT] = {lacc[0], lacc[1], lacc[2], lacc[3], l4, l5};
              float best = 0.f; int tok = 0;
#pragma unroll
              for (int v = 0; v < VT; ++v) {
                float val = l[v] + gmb[((t & 1) * 32 + m) * 6 + v];
                if (v == 0 || val > best) { best = val; tok = v; }
              }
              float lmax = l[0];
#pragma unroll
              for (int v = 1; v < VT; ++v) lmax = fmaxf(lmax, l[v]);
              float s = 0.f;
#pragma unroll
              for (int v = 0; v < VT; ++v) s += expf(l[v] - lmax);
              float lp = (l[tok] - lmax) - logf(s);
              tlpp[m] += lp;
              const bool is_stop = (tok == VT - 1);
              unsigned len = ((st >> 4) & 7u) + (is_stop ? 0u : 1u);
#pragma unroll
              for (int v = 0; v < VT; ++v)
                out[(size_t)row * (TS * VT) + t * VT + v] = (v == tok) ? 1.0f : 0.0f;
              stp[m] = (unsigned)tok | (is_stop ? 8u : 0u) | (len << 4);
            } else {
#pragma unroll
              for (int v = 0; v < VT; ++v)
                out[(size_t)row * (TS * VT) + t * VT + v] = 0.0f;
              stp[m] = 6u | 8u | (st & 0x70u);
            }
          }
        } else if (t + 1 < TS) {
          gen_gumbel(gmb, t + 1, b0, w4 - 2, lane, keys.a[t + 1], keys.b[t + 1]);
        }
      }
    } else if (ph == 33) {
      // ---- EPI: total_log_prob + lengths ----
      if (tid4 < 32) {
        const int row = b0 + tid4;
        out[(size_t)NB * (TS * VT) + row]      = tlpp[tid4];
        out[(size_t)NB * (TS * VT) + NB + row] = (float)((stp[tid4] >> 4) & 7u);
      }
    }
    __syncthreads();   // slot boundary: halves swap GEMM/VALU roles
  }
}

extern "C" void kernel_launch(void* const* d_in, const int* in_sizes, int n_in,
                              void* d_out, int out_size, void* d_ws, size_t ws_size,
                              hipStream_t stream) {
  (void)in_sizes; (void)n_in; (void)out_size; (void)ws_size;
  const float* x          = (const float*)d_in[0];
  const float* W_enc      = (const float*)d_in[1];
  const float* b_enc      = (const float*)d_in[2];
  const float* W_embed    = (const float*)d_in[3];
  const float* b_embed    = (const float*)d_in[4];
  const float* W_z        = (const float*)d_in[5];
  const float* b_z        = (const float*)d_in[6];
  const float* W_r        = (const float*)d_in[7];
  const float* b_r        = (const float*)d_in[8];
  const float* W_h        = (const float*)d_in[9];
  const float* b_h        = (const float*)d_in[10];
  const float* W_out      = (const float*)d_in[11];
  const float* b_out      = (const float*)d_in[12];
  const float* start_embed= (const float*)d_in[13];
  float* out = (float*)d_out;

  // workspace: pre [0,24576); enc frags [24576,221184); z [221184,614400);
  // r [614400,1007616); h [1007616,1400832); wout frags [1400832,1425408)
  float* pre = (float*)d_ws;
  unsigned short* encf = (unsigned short*)((char*)d_ws + 24576);
  unsigned short* zfb  = (unsigned short*)((char*)d_ws + 221184);
  unsigned short* rfb  = (unsigned short*)((char*)d_ws + 614400);
  unsigned short* hfb  = (unsigned short*)((char*)d_ws + 1007616);
  unsigned short* wof  = (unsigned short*)((char*)d_ws + 1400832);

  pre_kernel<<<138, 256, 0, stream>>>(W_enc, W_embed, b_embed, start_embed,
                                      W_z, b_z, W_r, b_r, W_h, b_h, W_out,
                                      pre, encf, zfb, rfb, hfb, wof);

  // keys = jax.random.split(jax.random.key(42), 6), partitionable mode
  Keys K;
  for (int t = 0; t < 6; ++t) {
    uint32_t o0, o1;
    tf2x32(0u, 42u, 0u, (uint32_t)t, o0, o1);
    K.a[t] = o0; K.b[t] = o1;
  }

  main_kernel<<<NB / BM, NTH, 0, stream>>>(x, b_enc, b_out,
                                           pre, encf, zfb, rfb, hfb, wof, out, K);
}

// Round 2
// 2110.367 us; speedup vs baseline: 3.2371x; 3.2371x over previous
//
#include <hip/hip_runtime.h>
#include <stdint.h>

// Problem constants
#define NB   131072
#define DIN  128
#define HD   256
#define VT   6
#define TS   6
// Tiling: BM=64 rows/block as TWO independent 32-row half-pipelines.
// 512 threads = 8 waves; waves 0-3 = half A (rows 0-31), waves 4-7 = half B
// (rows 32-63). Half B runs exactly one barrier interval behind half A via a
// STATIC schedule (straight-line code, uniform branch per interval), so each
// __syncthreads interval pairs one half's GEMM (MFMA pipe) with the other
// half's activation/pack (VALU pipe). No runtime phase dispatch -> state
// stays in registers (Round-0 regression was scratch spill from a dynamic
// phase loop: WRITE_SIZE 54MB -> 11.9GB).
// MFMA 16x16x32 bf16; fp32 exact via 3-plane bf16 split (6 products).
#define BM   64
#define NTH  512

typedef __attribute__((ext_vector_type(8))) short bfrag;   // 8 bf16 (4 VGPRs)
typedef __attribute__((ext_vector_type(4))) short bh4;     // 4 bf16
typedef __attribute__((ext_vector_type(4))) float f32x4;   // MFMA C/D

struct Keys { uint32_t a[6]; uint32_t b[6]; };

// hp plane layout: [p][kc][nt 2][lane 64][8] shorts, +16-short pad per (p,kc) block.
#define HPS(p, kc, nt, lp, j) ((((p) * 8 + (kc)) * 1040) + (nt) * 512 + (lp) * 8 + (j))
#define HPHALF (3 * 8 * 1040)   // shorts per 32-row half = 24,960 (49,920 B)

// ---- JAX threefry2x32 (20 rounds), bit-exact ----
__host__ __device__ inline void tf2x32(uint32_t k0, uint32_t k1,
                                       uint32_t c0, uint32_t c1,
                                       uint32_t& o0, uint32_t& o1) {
  uint32_t ks2 = k0 ^ k1 ^ 0x1BD11BDAu;
  uint32_t x0 = c0 + k0, x1 = c1 + k1;
#define TFR(d) { x0 += x1; x1 = (x1 << (d)) | (x1 >> (32 - (d))); x1 ^= x0; }
  TFR(13) TFR(15) TFR(26) TFR(6)
  x0 += k1;  x1 += ks2 + 1u;
  TFR(17) TFR(29) TFR(16) TFR(24)
  x0 += ks2; x1 += k0 + 2u;
  TFR(13) TFR(15) TFR(26) TFR(6)
  x0 += k0;  x1 += k1 + 3u;
  TFR(17) TFR(29) TFR(16) TFR(24)
  x0 += k1;  x1 += ks2 + 4u;
  TFR(13) TFR(15) TFR(26) TFR(6)
  x0 += ks2; x1 += k0 + 5u;
#undef TFR
  o0 = x0; o1 = x1;
}

__device__ __forceinline__ unsigned short f2bf(float x) {   // RNE f32->bf16
  uint32_t b = __float_as_uint(x);
  uint32_t r = b + 0x7FFFu + ((b >> 16) & 1u);
  return (unsigned short)(r >> 16);
}
__device__ __forceinline__ float bf2f(unsigned short u) {
  return __uint_as_float(((uint32_t)u) << 16);
}
__device__ __forceinline__ float sigf(float v) { return 1.0f / (1.0f + expf(-v)); }

#define MFMA16(a, b, c) __builtin_amdgcn_mfma_f32_16x16x32_bf16((a), (b), (c), 0, 0, 0)

// 6-product bf16x3: (hi,hi),(hi,mid),(mid,hi),(mid,mid),(hi,lo),(lo,hi)
__device__ __forceinline__ f32x4 prod6(const bfrag A[3], bfrag B0, bfrag B1, bfrag B2,
                                       f32x4 c) {
  c = MFMA16(A[0], B0, c);
  c = MFMA16(A[0], B1, c);
  c = MFMA16(A[1], B0, c);
  c = MFMA16(A[1], B1, c);
  c = MFMA16(A[0], B2, c);
  c = MFMA16(A[2], B0, c);
  return c;
}

// ---- Kernel A: pre tables (gate bias folded), W frags, W_out frags ----
// A-layout: ((p*KC + kc)*16 + mt)*512 + lane*8 + j holds
// A[m = mt*16 + (lane&15)][k = kc*32 + (lane>>4)*8 + j] = W[krow0+k][m].
__global__ void pre_kernel(const float* __restrict__ W_enc,
                           const float* __restrict__ W_embed,
                           const float* __restrict__ b_embed,
                           const float* __restrict__ start_embed,
                           const float* __restrict__ W_z, const float* __restrict__ b_z,
                           const float* __restrict__ W_r, const float* __restrict__ b_r,
                           const float* __restrict__ W_h, const float* __restrict__ b_h,
                           const float* __restrict__ W_out,
                           float* __restrict__ pre,
                           unsigned short* __restrict__ encf,
                           unsigned short* __restrict__ zf,
                           unsigned short* __restrict__ rf,
                           unsigned short* __restrict__ hf,
                           unsigned short* __restrict__ woutf) {
  const int bid = blockIdx.x;
  if (bid < 24) {  // pre tables: codes 0..5 = W_embed[c]+b_embed, 6 = b_embed, 7 = start
    __shared__ float xin[HD];
    const int c = bid & 7, g = bid >> 3, j = threadIdx.x;
    float v;
    if (c < 6)       v = W_embed[c * HD + j] + b_embed[j];
    else if (c == 6) v = b_embed[j];
    else             v = start_embed[j];
    xin[j] = v;
    __syncthreads();
    const float* Wg = (g == 0) ? W_z : (g == 1) ? W_r : W_h;  // top half rows 0..255
    const float* bg = (g == 0) ? b_z : (g == 1) ? b_r : b_h;
    float acc = bg[j];                       // fold gate bias into pre table
    for (int k = 0; k < HD; ++k) acc += xin[k] * Wg[k * HD + j];
    pre[(g * 8 + c) * HD + j] = acc;
    return;
  }
  if (bid >= 136) {  // W_out frags: single mt, KC=8; A[m][k] = W_out[k][m] (m<6)
    int id2 = (bid - 136) * 256 + threadIdx.x;   // 0..511
    int kc = id2 >> 6, lane = id2 & 63;
    int m = lane & 15, k0 = kc * 32 + ((lane >> 4) & 3) * 8;
    __align__(16) unsigned short P[3][8];
#pragma unroll
    for (int j = 0; j < 8; ++j) {
      float w = (m < VT) ? W_out[(size_t)(k0 + j) * VT + m] : 0.f;
      unsigned short h1 = f2bf(w);  float r1 = w - bf2f(h1);
      unsigned short h2 = f2bf(r1); float r2 = r1 - bf2f(h2);
      P[0][j] = h1; P[1][j] = h2; P[2][j] = f2bf(r2);
    }
    for (int p = 0; p < 3; ++p) {
      unsigned short* d = woutf + ((size_t)(p * 8 + kc) * 512) + (size_t)lane * 8;
      *(uint4*)d = *(const uint4*)P[p];
    }
    return;
  }
  int id = (bid - 24) * 256 + threadIdx.x;   // 0 .. 28671
  const float* src; unsigned short* dst; int kc, mt, lane, KC, krow0;
  if (id < 4096) {            // encoder frags: KC=4 (K=128)
    lane = id & 63; mt = (id >> 6) & 15; kc = id >> 10;
    src = W_enc; dst = encf; KC = 4; krow0 = 0;
  } else {                    // gate frags: KC=8 (K=256), bottom half rows 256..511
    int rem = id - 4096; int g = rem >> 13; int rr = rem & 8191;
    lane = rr & 63; mt = (rr >> 6) & 15; kc = rr >> 10;
    src = (g == 0) ? W_z : (g == 1) ? W_r : W_h;
    dst = (g == 0) ? zf  : (g == 1) ? rf  : hf;
    KC = 8; krow0 = 256;
  }
  const int m  = mt * 16 + (lane & 15);
  const int k0 = kc * 32 + ((lane >> 4) & 3) * 8;
  __align__(16) unsigned short P[3][8];
#pragma unroll
  for (int j = 0; j < 8; ++j) {
    float w = src[(size_t)(krow0 + k0 + j) * HD + m];
    unsigned short h1 = f2bf(w);  float r1 = w - bf2f(h1);
    unsigned short h2 = f2bf(r1); float r2 = r1 - bf2f(h2);
    P[0][j] = h1; P[1][j] = h2; P[2][j] = f2bf(r2);   // hi+mid+lo == w exactly
  }
  for (int p = 0; p < 3; ++p) {
    unsigned short* d = dst + ((size_t)(p * KC + kc) * 16 + mt) * 512 + (size_t)lane * 8;
    *(uint4*)d = *(const uint4*)P[p];
  }
}

// GEMM pass: A = W frags (global/L2), B = h planes (LDS, conflict-free).
// Wave owns mt = w4*4 + mtl. NG=2 shares B across two A streams (z+r fused).
template<int KC, int NG>
__device__ __forceinline__ void gemm_pass(const unsigned short* __restrict__ f0,
                                          const unsigned short* __restrict__ f1,
                                          const unsigned short* hp,
                                          int w4, int lane,
                                          f32x4 acc0[4][2], f32x4 acc1[4][2]) {
#pragma unroll 1
  for (int kc = 0; kc < KC; ++kc) {
    bfrag B[3][2];
#pragma unroll
    for (int p = 0; p < 3; ++p)
#pragma unroll
      for (int nt = 0; nt < 2; ++nt)
        B[p][nt] = *(const bfrag*)&hp[HPS(p, kc, nt, lane, 0)];
#pragma unroll
    for (int mtl = 0; mtl < 4; ++mtl) {
      const int fo = (kc * 16 + w4 * 4 + mtl) * 512 + lane * 8;
      bfrag A0[3], A1[3];
#pragma unroll
      for (int p = 0; p < 3; ++p) A0[p] = *(const bfrag*)(f0 + fo + p * (KC * 8192));
      if (NG == 2) {
#pragma unroll
        for (int p = 0; p < 3; ++p) A1[p] = *(const bfrag*)(f1 + fo + p * (KC * 8192));
      }
#pragma unroll
      for (int nt = 0; nt < 2; ++nt) {
        acc0[mtl][nt] = prod6(A0, B[0][nt], B[1][nt], B[2][nt], acc0[mtl][nt]);
        if (NG == 2)
          acc1[mtl][nt] = prod6(A1, B[0][nt], B[1][nt], B[2][nt], acc1[mtl][nt]);
      }
    }
  }
}

// gumbel batch for step s, tile (16 rows), into double-buffered LDS (per half)
__device__ __forceinline__ void gen_gumbel(float* __restrict__ gmb, int s, int b0,
                                           int tile, int lane,
                                           uint32_t ka, uint32_t kb) {
  uint32_t basej = (uint32_t)(b0 + tile * 16) * 6u;
#pragma unroll
  for (int rep = 0; rep < 2; ++rep) {
    int d = rep * 64 + lane;
    if (d < 96) {
      uint32_t o0, o1;
      tf2x32(ka, kb, 0u, basej + (uint32_t)d, o0, o1);
      uint32_t bits = o0 ^ o1;
      float f = __uint_as_float((bits >> 9) | 0x3f800000u) - 1.0f;
      float u = (f > 0.f) ? f : 1.175494350822288e-38f;
      float lg1 = (float)log((double)u);
      float lg2 = (float)log((double)(-lg1));
      gmb[((s & 1) * 32 + tile * 16 + d / 6) * 6 + (d % 6)] = -lg2;
    }
  }
}

// ---- main kernel: persistent rollout; h_old in registers; logits via MFMA.
// Static one-interval skew between the two 32-row halves (see top comment).
// Per-row math is bit-identical to the BM=32 version, so outputs unchanged.
__launch_bounds__(NTH, 2)
__global__ void main_kernel(const float* __restrict__ x,
                            const float* __restrict__ b_enc,
                            const float* __restrict__ b_out,
                            const float* __restrict__ pre,
                            const unsigned short* __restrict__ encf,
                            const unsigned short* __restrict__ zf,
                            const unsigned short* __restrict__ rf,
                            const unsigned short* __restrict__ hf,
                            const unsigned short* __restrict__ woutf,
                            float* __restrict__ out, Keys keys) {
  __shared__ __align__(16) unsigned short hp_s[2 * HPHALF];    // 99,840 B
  __shared__ float gmb_s[2 * 2 * 32 * 6];                      //  3,072 B
  __shared__ float boutL[16];
  __shared__ unsigned state_s[2 * 32];
  __shared__ float tlp_s[2 * 32];
  // total ~103.5 KB -> 1 block/CU (8 waves; overlap is in-block by design)

  const int tid  = threadIdx.x;
  const int wave = tid >> 6, lane = tid & 63;
  const int grp  = wave >> 2;          // 0 = half A, 1 = half B
  const int w4   = wave & 3;           // wave-in-half
  const int ln   = lane & 15, qk = lane >> 4;
  const int tid4 = tid & 255;          // thread-in-half
  const int b0   = blockIdx.x * BM + grp * 32;

  unsigned short* hp   = hp_s    + grp * HPHALF;
  float*          gmb  = gmb_s   + grp * (2 * 32 * 6);
  unsigned*       stp  = state_s + grp * 32;
  float*          tlpp = tlp_s   + grp * 32;

  f32x4 acc0[4][2], acc1[4][2], z_s[4][2], hold[4][2];

  // ---- phase bodies (inlined lambdas; all per-half state by reference) ----
  auto PH_STAGE = [&]() {
    // x -> B-operand planes for this half's 32 rows; init state; step-0 gumbels
    if (tid4 < 16) boutL[tid4] = (tid4 < VT) ? b_out[tid4] : 0.f;
    if (tid4 < 32) { stp[tid4] = 7u; tlpp[tid4] = 0.f; }
    for (int i = tid4; i < 32 * DIN; i += 256) {
      int row = i >> 7, k = i & 127;
      float v = x[(size_t)(b0 + row) * DIN + k];
      unsigned short h1 = f2bf(v);  float r1 = v - bf2f(h1);
      unsigned short h2 = f2bf(r1); float r2 = r1 - bf2f(h2);
      int kc = k >> 5, nt = row >> 4, lp = (row & 15) + 16 * ((k >> 3) & 3), j = k & 7;
      hp[HPS(0, kc, nt, lp, j)] = h1;
      hp[HPS(1, kc, nt, lp, j)] = h2;
      hp[HPS(2, kc, nt, lp, j)] = f2bf(r2);
    }
    if (w4 >= 2) gen_gumbel(gmb, 0, b0, w4 - 2, lane, keys.a[0], keys.b[0]);
  };

  auto PH_GENC = [&]() {            // h0 = x @ W_enc + b_enc
#pragma unroll
    for (int mtl = 0; mtl < 4; ++mtl) {
      int mb = (w4 * 4 + mtl) * 16 + qk * 4;
      f32x4 be = *(const f32x4*)&b_enc[mb];
#pragma unroll
      for (int nt = 0; nt < 2; ++nt) acc0[mtl][nt] = be;
    }
    gemm_pass<4, 1>(encf, nullptr, hp, w4, lane, acc0, acc1);
  };

  auto PH_PENC = [&]() {            // split h0, publish planes; h_old -> regs
#pragma unroll
    for (int mtl = 0; mtl < 4; ++mtl) {
      int mb = (w4 * 4 + mtl) * 16 + qk * 4;
      int kc = mb >> 5, hi2 = (mb >> 3) & 3, j0 = mb & 7, lp = ln + 16 * hi2;
#pragma unroll
      for (int nt = 0; nt < 2; ++nt) {
        f32x4 o = acc0[mtl][nt];
        hold[mtl][nt] = o;
        bh4 P0, P1, P2;
#pragma unroll
        for (int j = 0; j < 4; ++j) {
          float v = o[j];
          unsigned short h1 = f2bf(v);  float r1 = v - bf2f(h1);
          unsigned short h2 = f2bf(r1); float r2 = r1 - bf2f(h2);
          P0[j] = (short)h1; P1[j] = (short)h2; P2[j] = (short)f2bf(r2);
        }
        *(bh4*)&hp[HPS(0, kc, nt, lp, j0)] = P0;
        *(bh4*)&hp[HPS(1, kc, nt, lp, j0)] = P1;
        *(bh4*)&hp[HPS(2, kc, nt, lp, j0)] = P2;
      }
    }
  };

  auto PH_GZR = [&]() {             // fused z+r GEMM (C-init from pre tables)
#pragma unroll
    for (int mtl = 0; mtl < 4; ++mtl) {
      int mb = (w4 * 4 + mtl) * 16 + qk * 4;
#pragma unroll
      for (int nt = 0; nt < 2; ++nt) {
        int code = (int)(stp[nt * 16 + ln] & 7u);
        acc0[mtl][nt] = *(const f32x4*)&pre[(0 * 8 + code) * 256 + mb];
        acc1[mtl][nt] = *(const f32x4*)&pre[(1 * 8 + code) * 256 + mb];
      }
    }
    gemm_pass<8, 2>(zf, rf, hp, w4, lane, acc0, acc1);
  };

  auto PH_PRH = [&]() {             // z = sig(.), rh = sig(.)*h_old; publish rh
#pragma unroll
    for (int mtl = 0; mtl < 4; ++mtl) {
      int mb = (w4 * 4 + mtl) * 16 + qk * 4;
      int kc = mb >> 5, hi2 = (mb >> 3) & 3, j0 = mb & 7, lp = ln + 16 * hi2;
#pragma unroll
      for (int nt = 0; nt < 2; ++nt) {
        f32x4 ho = hold[mtl][nt];
        f32x4 zv;
        bh4 P0, P1, P2;
#pragma unroll
        for (int j = 0; j < 4; ++j) {
          zv[j] = sigf(acc0[mtl][nt][j]);
          float rhv = sigf(acc1[mtl][nt][j]) * ho[j];
          unsigned short h1 = f2bf(rhv); float r1 = rhv - bf2f(h1);
          unsigned short h2 = f2bf(r1);  float r2 = r1 - bf2f(h2);
          P0[j] = (short)h1; P1[j] = (short)h2; P2[j] = (short)f2bf(r2);
        }
        z_s[mtl][nt] = zv;
        *(bh4*)&hp[HPS(0, kc, nt, lp, j0)] = P0;
        *(bh4*)&hp[HPS(1, kc, nt, lp, j0)] = P1;
        *(bh4*)&hp[HPS(2, kc, nt, lp, j0)] = P2;
      }
    }
  };

  auto PH_GH = [&]() {              // candidate gate GEMM
#pragma unroll
    for (int mtl = 0; mtl < 4; ++mtl) {
      int mb = (w4 * 4 + mtl) * 16 + qk * 4;
#pragma unroll
      for (int nt = 0; nt < 2; ++nt) {
        int code = (int)(stp[nt * 16 + ln] & 7u);
        acc0[mtl][nt] = *(const f32x4*)&pre[(2 * 8 + code) * 256 + mb];
      }
    }
    gemm_pass<8, 1>(hf, nullptr, hp, w4, lane, acc0, acc1);
  };

  auto PH_PH = [&]() {              // h_new = (1-z)h + z tanh(.); publish
#pragma unroll
    for (int mtl = 0; mtl < 4; ++mtl) {
      int mb = (w4 * 4 + mtl) * 16 + qk * 4;
      int kc = mb >> 5, hi2 = (mb >> 3) & 3, j0 = mb & 7, lp = ln + 16 * hi2;
#pragma unroll
      for (int nt = 0; nt < 2; ++nt) {
        f32x4 z = z_s[mtl][nt], ho = hold[mtl][nt], hn;
        bh4 P0, P1, P2;
#pragma unroll
        for (int j = 0; j < 4; ++j) {
          float ht = tanhf(acc0[mtl][nt][j]);
          hn[j] = (1.0f - z[j]) * ho[j] + z[j] * ht;
          unsigned short h1 = f2bf(hn[j]); float r1 = hn[j] - bf2f(h1);
          unsigned short h2 = f2bf(r1);    float r2 = r1 - bf2f(h2);
          P0[j] = (short)h1; P1[j] = (short)h2; P2[j] = (short)f2bf(r2);
        }
        hold[mtl][nt] = hn;              // persists to next step
        *(bh4*)&hp[HPS(0, kc, nt, lp, j0)] = P0;
        *(bh4*)&hp[HPS(1, kc, nt, lp, j0)] = P1;
        *(bh4*)&hp[HPS(2, kc, nt, lp, j0)] = P2;
      }
    }
  };

  auto PH_L = [&](int t) {          // logits+sample (w4<2) || gumbel t+1 (w4>=2)
    if (w4 < 2) {
      f32x4 lacc;
#pragma unroll
      for (int j = 0; j < 4; ++j) lacc[j] = boutL[qk * 4 + j];
#pragma unroll 1
      for (int kc = 0; kc < 8; ++kc) {
        bfrag B0 = *(const bfrag*)&hp[HPS(0, kc, w4, lane, 0)];
        bfrag B1 = *(const bfrag*)&hp[HPS(1, kc, w4, lane, 0)];
        bfrag B2 = *(const bfrag*)&hp[HPS(2, kc, w4, lane, 0)];
        bfrag A[3];
#pragma unroll
        for (int p = 0; p < 3; ++p)
          A[p] = *(const bfrag*)(woutf + (p * 8 + kc) * 512 + lane * 8);
        lacc = prod6(A, B0, B1, B2, lacc);
      }
      // D[m=qk*4+j][n=ln]: vocab 0..3 at qk=0, vocab 4..5 at qk=1 regs 0..1
      float l4 = __shfl(lacc[0], ln + 16, 64);
      float l5 = __shfl(lacc[1], ln + 16, 64);
      if (qk == 0) {
        const int m = w4 * 16 + ln;
        const int row = b0 + m;
        unsigned st = stp[m];
        if (!(st & 8u)) {
          float l[VT] = {lacc[0], lacc[1], lacc[2], lacc[3], l4, l5};
          float best = 0.f; int tok = 0;
#pragma unroll
          for (int v = 0; v < VT; ++v) {
            float val = l[v] + gmb[((t & 1) * 32 + m) * 6 + v];
            if (v == 0 || val > best) { best = val; tok = v; }
          }
          float lmax = l[0];
#pragma unroll
          for (int v = 1; v < VT; ++v) lmax = fmaxf(lmax, l[v]);
          float s = 0.f;
#pragma unroll
          for (int v = 0; v < VT; ++v) s += expf(l[v] - lmax);
          float lp = (l[tok] - lmax) - logf(s);
          tlpp[m] += lp;
          const bool is_stop = (tok == VT - 1);
          unsigned len = ((st >> 4) & 7u) + (is_stop ? 0u : 1u);
#pragma unroll
          for (int v = 0; v < VT; ++v)
            out[(size_t)row * (TS * VT) + t * VT + v] = (v == tok) ? 1.0f : 0.0f;
          stp[m] = (unsigned)tok | (is_stop ? 8u : 0u) | (len << 4);
        } else {
#pragma unroll
          for (int v = 0; v < VT; ++v)
            out[(size_t)row * (TS * VT) + t * VT + v] = 0.0f;
          stp[m] = 6u | 8u | (st & 0x70u);
        }
      }
    } else if (t + 1 < TS) {
      gen_gumbel(gmb, t + 1, b0, w4 - 2, lane, keys.a[t + 1], keys.b[t + 1]);
    }
  };

  auto PH_EPI = [&]() {             // total_log_prob + lengths
    if (tid4 < 32) {
      const int row = b0 + tid4;
      out[(size_t)NB * (TS * VT) + row]      = tlpp[tid4];
      out[(size_t)NB * (TS * VT) + NB + row] = (float)((stp[tid4] >> 4) & 7u);
    }
  };

  // ---- static skewed schedule: half B is one interval behind half A ----
  if (grp == 0) PH_STAGE();
  __syncthreads();
  if (grp == 0) PH_GENC(); else PH_STAGE();
  __syncthreads();
  if (grp == 0) PH_PENC(); else PH_GENC();
  __syncthreads();
  if (grp == 0) PH_GZR();  else PH_PENC();
  __syncthreads();
  if (grp == 0) PH_PRH();  else PH_GZR();
  __syncthreads();
  if (grp == 0) PH_GH();   else PH_PRH();
  __syncthreads();
  if (grp == 0) PH_PH();   else PH_GH();
  __syncthreads();
#pragma unroll 1
  for (int t = 0; t < TS - 1; ++t) {
    if (grp == 0) PH_L(t);  else PH_PH();
    __syncthreads();
    if (grp == 0) PH_GZR(); else PH_L(t);
    __syncthreads();
    if (grp == 0) PH_PRH(); else PH_GZR();
    __syncthreads();
    if (grp == 0) PH_GH();  else PH_PRH();
    __syncthreads();
    if (grp == 0) PH_PH();  else PH_GH();
    __syncthreads();
  }
  if (grp == 0) PH_L(TS - 1); else PH_PH();
  __syncthreads();
  if (grp == 0) PH_EPI();     else PH_L(TS - 1);
  __syncthreads();
  if (grp == 1) PH_EPI();
}

extern "C" void kernel_launch(void* const* d_in, const int* in_sizes, int n_in,
                              void* d_out, int out_size, void* d_ws, size_t ws_size,
                              hipStream_t stream) {
  (void)in_sizes; (void)n_in; (void)out_size; (void)ws_size;
  const float* x          = (const float*)d_in[0];
  const float* W_enc      = (const float*)d_in[1];
  const float* b_enc      = (const float*)d_in[2];
  const float* W_embed    = (const float*)d_in[3];
  const float* b_embed    = (const float*)d_in[4];
  const float* W_z        = (const float*)d_in[5];
  const float* b_z        = (const float*)d_in[6];
  const float* W_r        = (const float*)d_in[7];
  const float* b_r        = (const float*)d_in[8];
  const float* W_h        = (const float*)d_in[9];
  const float* b_h        = (const float*)d_in[10];
  const float* W_out      = (const float*)d_in[11];
  const float* b_out      = (const float*)d_in[12];
  const float* start_embed= (const float*)d_in[13];
  float* out = (float*)d_out;

  // workspace: pre [0,24576); enc frags [24576,221184); z [221184,614400);
  // r [614400,1007616); h [1007616,1400832); wout frags [1400832,1425408)
  float* pre = (float*)d_ws;
  unsigned short* encf = (unsigned short*)((char*)d_ws + 24576);
  unsigned short* zfb  = (unsigned short*)((char*)d_ws + 221184);
  unsigned short* rfb  = (unsigned short*)((char*)d_ws + 614400);
  unsigned short* hfb  = (unsigned short*)((char*)d_ws + 1007616);
  unsigned short* wof  = (unsigned short*)((char*)d_ws + 1400832);

  pre_kernel<<<138, 256, 0, stream>>>(W_enc, W_embed, b_embed, start_embed,
                                      W_z, b_z, W_r, b_r, W_h, b_h, W_out,
                                      pre, encf, zfb, rfb, hfb, wof);

  // keys = jax.random.split(jax.random.key(42), 6), partitionable mode
  Keys K;
  for (int t = 0; t < 6; ++t) {
    uint32_t o0, o1;
    tf2x32(0u, 42u, 0u, (uint32_t)t, o0, o1);
    K.a[t] = o0; K.b[t] = o1;
  }

  main_kernel<<<NB / BM, NTH, 0, stream>>>(x, b_enc, b_out,
                                           pre, encf, zfb, rfb, hfb, wof, out, K);
}

// Round 3
// 2057.488 us; speedup vs baseline: 3.3203x; 1.0257x over previous
//
#include <hip/hip_runtime.h>
#include <stdint.h>

// Problem constants
#define NB   131072
#define DIN  128
#define HD   256
#define VT   6
#define TS   6
// Tiling: BM=32 rows/block, 256 threads = 4 waves (wave owns 64 weight-cols).
// Occupancy attack: the old fused z+r GEMM held acc0+acc1+z_s+hold = 128 f32
// of live per-thread state -> ~256 unified VGPR/AGPR -> 2 waves/SIMD (the
// measured latency-bound 44% MfmaUtil). Splitting z and r into sequential
// passes (z acc folded into z_s via sigmoid before r starts) cuts peak live
// state ~32 regs; __launch_bounds__(256,3) targets 3 waves/SIMD (3 blocks/CU,
// LDS 3x52KB fits 160KB). Bitwise identical: each accumulator executes the
// exact same MFMA sequence (kc ascending, prod6 order) as in the fused form.
// MFMA 16x16x32 bf16; fp32 exact via 3-plane bf16 split (6 products).
#define BM   32
#define NTH  256

typedef __attribute__((ext_vector_type(8))) short bfrag;   // 8 bf16 (4 VGPRs)
typedef __attribute__((ext_vector_type(4))) short bh4;     // 4 bf16
typedef __attribute__((ext_vector_type(4))) float f32x4;   // MFMA C/D

struct Keys { uint32_t a[6]; uint32_t b[6]; };

// hp plane layout: [p][kc][nt 2][lane 64][8] shorts, +16-short pad per (p,kc) block.
#define HPS(p, kc, nt, lp, j) ((((p) * 8 + (kc)) * 1040) + (nt) * 512 + (lp) * 8 + (j))

// ---- JAX threefry2x32 (20 rounds), bit-exact ----
__host__ __device__ inline void tf2x32(uint32_t k0, uint32_t k1,
                                       uint32_t c0, uint32_t c1,
                                       uint32_t& o0, uint32_t& o1) {
  uint32_t ks2 = k0 ^ k1 ^ 0x1BD11BDAu;
  uint32_t x0 = c0 + k0, x1 = c1 + k1;
#define TFR(d) { x0 += x1; x1 = (x1 << (d)) | (x1 >> (32 - (d))); x1 ^= x0; }
  TFR(13) TFR(15) TFR(26) TFR(6)
  x0 += k1;  x1 += ks2 + 1u;
  TFR(17) TFR(29) TFR(16) TFR(24)
  x0 += ks2; x1 += k0 + 2u;
  TFR(13) TFR(15) TFR(26) TFR(6)
  x0 += k0;  x1 += k1 + 3u;
  TFR(17) TFR(29) TFR(16) TFR(24)
  x0 += k1;  x1 += ks2 + 4u;
  TFR(13) TFR(15) TFR(26) TFR(6)
  x0 += ks2; x1 += k0 + 5u;
#undef TFR
  o0 = x0; o1 = x1;
}

__device__ __forceinline__ unsigned short f2bf(float x) {   // RNE f32->bf16
  uint32_t b = __float_as_uint(x);
  uint32_t r = b + 0x7FFFu + ((b >> 16) & 1u);
  return (unsigned short)(r >> 16);
}
__device__ __forceinline__ float bf2f(unsigned short u) {
  return __uint_as_float(((uint32_t)u) << 16);
}
__device__ __forceinline__ float sigf(float v) { return 1.0f / (1.0f + expf(-v)); }

#define MFMA16(a, b, c) __builtin_amdgcn_mfma_f32_16x16x32_bf16((a), (b), (c), 0, 0, 0)

// 6-product bf16x3: (hi,hi),(hi,mid),(mid,hi),(mid,mid),(hi,lo),(lo,hi)
__device__ __forceinline__ f32x4 prod6(const bfrag A[3], bfrag B0, bfrag B1, bfrag B2,
                                       f32x4 c) {
  c = MFMA16(A[0], B0, c);
  c = MFMA16(A[0], B1, c);
  c = MFMA16(A[1], B0, c);
  c = MFMA16(A[1], B1, c);
  c = MFMA16(A[0], B2, c);
  c = MFMA16(A[2], B0, c);
  return c;
}

// ---- Kernel A: pre tables (gate bias folded), W frags, W_out frags ----
// A-layout: ((p*KC + kc)*16 + mt)*512 + lane*8 + j holds
// A[m = mt*16 + (lane&15)][k = kc*32 + (lane>>4)*8 + j] = W[krow0+k][m].
__global__ void pre_kernel(const float* __restrict__ W_enc,
                           const float* __restrict__ W_embed,
                           const float* __restrict__ b_embed,
                           const float* __restrict__ start_embed,
                           const float* __restrict__ W_z, const float* __restrict__ b_z,
                           const float* __restrict__ W_r, const float* __restrict__ b_r,
                           const float* __restrict__ W_h, const float* __restrict__ b_h,
                           const float* __restrict__ W_out,
                           float* __restrict__ pre,
                           unsigned short* __restrict__ encf,
                           unsigned short* __restrict__ zf,
                           unsigned short* __restrict__ rf,
                           unsigned short* __restrict__ hf,
                           unsigned short* __restrict__ woutf) {
  const int bid = blockIdx.x;
  if (bid < 24) {  // pre tables: codes 0..5 = W_embed[c]+b_embed, 6 = b_embed, 7 = start
    __shared__ float xin[HD];
    const int c = bid & 7, g = bid >> 3, j = threadIdx.x;
    float v;
    if (c < 6)       v = W_embed[c * HD + j] + b_embed[j];
    else if (c == 6) v = b_embed[j];
    else             v = start_embed[j];
    xin[j] = v;
    __syncthreads();
    const float* Wg = (g == 0) ? W_z : (g == 1) ? W_r : W_h;  // top half rows 0..255
    const float* bg = (g == 0) ? b_z : (g == 1) ? b_r : b_h;
    float acc = bg[j];                       // fold gate bias into pre table
    for (int k = 0; k < HD; ++k) acc += xin[k] * Wg[k * HD + j];
    pre[(g * 8 + c) * HD + j] = acc;
    return;
  }
  if (bid >= 136) {  // W_out frags: single mt, KC=8; A[m][k] = W_out[k][m] (m<6)
    int id2 = (bid - 136) * 256 + threadIdx.x;   // 0..511
    int kc = id2 >> 6, lane = id2 & 63;
    int m = lane & 15, k0 = kc * 32 + ((lane >> 4) & 3) * 8;
    __align__(16) unsigned short P[3][8];
#pragma unroll
    for (int j = 0; j < 8; ++j) {
      float w = (m < VT) ? W_out[(size_t)(k0 + j) * VT + m] : 0.f;
      unsigned short h1 = f2bf(w);  float r1 = w - bf2f(h1);
      unsigned short h2 = f2bf(r1); float r2 = r1 - bf2f(h2);
      P[0][j] = h1; P[1][j] = h2; P[2][j] = f2bf(r2);
    }
    for (int p = 0; p < 3; ++p) {
      unsigned short* d = woutf + ((size_t)(p * 8 + kc) * 512) + (size_t)lane * 8;
      *(uint4*)d = *(const uint4*)P[p];
    }
    return;
  }
  int id = (bid - 24) * 256 + threadIdx.x;   // 0 .. 28671
  const float* src; unsigned short* dst; int kc, mt, lane, KC, krow0;
  if (id < 4096) {            // encoder frags: KC=4 (K=128)
    lane = id & 63; mt = (id >> 6) & 15; kc = id >> 10;
    src = W_enc; dst = encf; KC = 4; krow0 = 0;
  } else {                    // gate frags: KC=8 (K=256), bottom half rows 256..511
    int rem = id - 4096; int g = rem >> 13; int rr = rem & 8191;
    lane = rr & 63; mt = (rr >> 6) & 15; kc = rr >> 10;
    src = (g == 0) ? W_z : (g == 1) ? W_r : W_h;
    dst = (g == 0) ? zf  : (g == 1) ? rf  : hf;
    KC = 8; krow0 = 256;
  }
  const int m  = mt * 16 + (lane & 15);
  const int k0 = kc * 32 + ((lane >> 4) & 3) * 8;
  __align__(16) unsigned short P[3][8];
#pragma unroll
  for (int j = 0; j < 8; ++j) {
    float w = src[(size_t)(krow0 + k0 + j) * HD + m];
    unsigned short h1 = f2bf(w);  float r1 = w - bf2f(h1);
    unsigned short h2 = f2bf(r1); float r2 = r1 - bf2f(h2);
    P[0][j] = h1; P[1][j] = h2; P[2][j] = f2bf(r2);   // hi+mid+lo == w exactly
  }
  for (int p = 0; p < 3; ++p) {
    unsigned short* d = dst + ((size_t)(p * KC + kc) * 16 + mt) * 512 + (size_t)lane * 8;
    *(uint4*)d = *(const uint4*)P[p];
  }
}

// GEMM pass: A = W frags (global/L2), B = h planes (LDS, conflict-free).
// Wave owns mt = wave*4 + mtl. Single accumulator stream (z/r split keeps
// peak register state low -> 3 waves/SIMD).
template<int KC>
__device__ __forceinline__ void gemm_pass(const unsigned short* __restrict__ f0,
                                          const unsigned short* hp_s,
                                          int wave, int lane,
                                          f32x4 acc[4][2]) {
#pragma unroll 1
  for (int kc = 0; kc < KC; ++kc) {
    bfrag B[3][2];
#pragma unroll
    for (int p = 0; p < 3; ++p)
#pragma unroll
      for (int nt = 0; nt < 2; ++nt)
        B[p][nt] = *(const bfrag*)&hp_s[HPS(p, kc, nt, lane, 0)];
#pragma unroll
    for (int mtl = 0; mtl < 4; ++mtl) {
      const int fo = (kc * 16 + wave * 4 + mtl) * 512 + lane * 8;
      bfrag A0[3];
#pragma unroll
      for (int p = 0; p < 3; ++p) A0[p] = *(const bfrag*)(f0 + fo + p * (KC * 8192));
#pragma unroll
      for (int nt = 0; nt < 2; ++nt)
        acc[mtl][nt] = prod6(A0, B[0][nt], B[1][nt], B[2][nt], acc[mtl][nt]);
    }
  }
}

// gumbel batch for step s, tile (16 rows), into double-buffered LDS
__device__ __forceinline__ void gen_gumbel(float* __restrict__ gmb, int s, int b0,
                                           int tile, int lane,
                                           uint32_t ka, uint32_t kb) {
  uint32_t basej = (uint32_t)(b0 + tile * 16) * 6u;
#pragma unroll
  for (int rep = 0; rep < 2; ++rep) {
    int d = rep * 64 + lane;
    if (d < 96) {
      uint32_t o0, o1;
      tf2x32(ka, kb, 0u, basej + (uint32_t)d, o0, o1);
      uint32_t bits = o0 ^ o1;
      float f = __uint_as_float((bits >> 9) | 0x3f800000u) - 1.0f;
      float u = (f > 0.f) ? f : 1.175494350822288e-38f;
      float lg1 = (float)log((double)u);
      float lg2 = (float)log((double)(-lg1));
      gmb[((s & 1) * 32 + tile * 16 + d / 6) * 6 + (d % 6)] = -lg2;
    }
  }
}

// ---- main kernel: persistent rollout; h_old in registers; logits via MFMA;
// gumbels generated by waves 2-3 overlapped with waves 0-1's logits GEMM.
__launch_bounds__(NTH, 3)
__global__ void main_kernel(const float* __restrict__ x,
                            const float* __restrict__ b_enc,
                            const float* __restrict__ b_out,
                            const float* __restrict__ pre,
                            const unsigned short* __restrict__ encf,
                            const unsigned short* __restrict__ zf,
                            const unsigned short* __restrict__ rf,
                            const unsigned short* __restrict__ hf,
                            const unsigned short* __restrict__ woutf,
                            float* __restrict__ out, Keys keys) {
  __shared__ __align__(16) unsigned short hp_s[3 * 8 * 1040];  // 49,920 B
  __shared__ float gmb_s[2 * 32 * 6];                          //  1,536 B
  __shared__ float boutL[16];
  __shared__ unsigned state[BM];
  __shared__ float tlp[BM];
  // total ~51.8 KB -> 3 blocks/CU (register-permitting)

  const int tid = threadIdx.x;
  const int wave = tid >> 6, lane = tid & 63;
  const int ln = lane & 15, qk = lane >> 4;
  const int b0 = blockIdx.x * BM;

  if (tid < 16) boutL[tid] = (tid < VT) ? b_out[tid] : 0.f;
  if (tid < BM) { state[tid] = 7u; tlp[tid] = 0.f; }

  // stage x (B-operand planes), kc 0..3
  for (int i = tid; i < BM * DIN; i += NTH) {
    int row = i >> 7, k = i & 127;
    float v = x[(size_t)(b0 + row) * DIN + k];
    unsigned short h1 = f2bf(v);  float r1 = v - bf2f(h1);
    unsigned short h2 = f2bf(r1); float r2 = r1 - bf2f(h2);
    int kc = k >> 5, nt = row >> 4, lp = (row & 15) + 16 * ((k >> 3) & 3), j = k & 7;
    hp_s[HPS(0, kc, nt, lp, j)] = h1;
    hp_s[HPS(1, kc, nt, lp, j)] = h2;
    hp_s[HPS(2, kc, nt, lp, j)] = f2bf(r2);
  }
  // waves 2-3: generate step-0 gumbels while others head to barrier
  if (wave >= 2) gen_gumbel(gmb_s, 0, b0, wave - 2, lane, keys.a[0], keys.b[0]);
  __syncthreads();

  f32x4 acc0[4][2], z_s[4][2], hold[4][2];

  // ---- encoder: h0 = x @ W_enc + b_enc ----
#pragma unroll
  for (int mtl = 0; mtl < 4; ++mtl) {
    int mb = (wave * 4 + mtl) * 16 + qk * 4;
    f32x4 be = *(const f32x4*)&b_enc[mb];
#pragma unroll
    for (int nt = 0; nt < 2; ++nt) acc0[mtl][nt] = be;
  }
  gemm_pass<4>(encf, hp_s, wave, lane, acc0);
  __syncthreads();  // all x-plane reads done
#pragma unroll
  for (int mtl = 0; mtl < 4; ++mtl) {
    int mb = (wave * 4 + mtl) * 16 + qk * 4;
    int kc = mb >> 5, hi2 = (mb >> 3) & 3, j0 = mb & 7, lp = ln + 16 * hi2;
#pragma unroll
    for (int nt = 0; nt < 2; ++nt) {
      f32x4 o = acc0[mtl][nt];
      hold[mtl][nt] = o;                 // h_old lives in registers from here on
      bh4 P0, P1, P2;
#pragma unroll
      for (int j = 0; j < 4; ++j) {
        float v = o[j];
        unsigned short h1 = f2bf(v);  float r1 = v - bf2f(h1);
        unsigned short h2 = f2bf(r1); float r2 = r1 - bf2f(h2);
        P0[j] = (short)h1; P1[j] = (short)h2; P2[j] = (short)f2bf(r2);
      }
      *(bh4*)&hp_s[HPS(0, kc, nt, lp, j0)] = P0;
      *(bh4*)&hp_s[HPS(1, kc, nt, lp, j0)] = P1;
      *(bh4*)&hp_s[HPS(2, kc, nt, lp, j0)] = P2;
    }
  }
  __syncthreads();

#pragma unroll 1
  for (int t = 0; t < TS; ++t) {
    // ---- z gate (C-init from pre tables incl. bias); acc folded into z_s ----
#pragma unroll
    for (int mtl = 0; mtl < 4; ++mtl) {
      int mb = (wave * 4 + mtl) * 16 + qk * 4;
#pragma unroll
      for (int nt = 0; nt < 2; ++nt) {
        int code = (int)(state[nt * 16 + ln] & 7u);
        acc0[mtl][nt] = *(const f32x4*)&pre[(0 * 8 + code) * 256 + mb];
      }
    }
    gemm_pass<8>(zf, hp_s, wave, lane, acc0);
#pragma unroll
    for (int mtl = 0; mtl < 4; ++mtl)
#pragma unroll
      for (int nt = 0; nt < 2; ++nt)
#pragma unroll
        for (int j = 0; j < 4; ++j)
          z_s[mtl][nt][j] = sigf(acc0[mtl][nt][j]);   // frees acc for r pass
    // ---- r gate (same h planes; same barrier interval) ----
#pragma unroll
    for (int mtl = 0; mtl < 4; ++mtl) {
      int mb = (wave * 4 + mtl) * 16 + qk * 4;
#pragma unroll
      for (int nt = 0; nt < 2; ++nt) {
        int code = (int)(state[nt * 16 + ln] & 7u);
        acc0[mtl][nt] = *(const f32x4*)&pre[(1 * 8 + code) * 256 + mb];
      }
    }
    gemm_pass<8>(rf, hp_s, wave, lane, acc0);
    __syncthreads();  // all h-plane reads (z and r passes) done
#pragma unroll
    for (int mtl = 0; mtl < 4; ++mtl) {
      int mb = (wave * 4 + mtl) * 16 + qk * 4;
      int kc = mb >> 5, hi2 = (mb >> 3) & 3, j0 = mb & 7, lp = ln + 16 * hi2;
#pragma unroll
      for (int nt = 0; nt < 2; ++nt) {
        f32x4 ho = hold[mtl][nt];
        bh4 P0, P1, P2;
#pragma unroll
        for (int j = 0; j < 4; ++j) {
          float rhv = sigf(acc0[mtl][nt][j]) * ho[j];
          unsigned short h1 = f2bf(rhv); float r1 = rhv - bf2f(h1);
          unsigned short h2 = f2bf(r1);  float r2 = r1 - bf2f(h2);
          P0[j] = (short)h1; P1[j] = (short)h2; P2[j] = (short)f2bf(r2);
        }
        *(bh4*)&hp_s[HPS(0, kc, nt, lp, j0)] = P0;
        *(bh4*)&hp_s[HPS(1, kc, nt, lp, j0)] = P1;
        *(bh4*)&hp_s[HPS(2, kc, nt, lp, j0)] = P2;
      }
    }
    __syncthreads();  // rh planes published

    // ---- candidate gate ----
#pragma unroll
    for (int mtl = 0; mtl < 4; ++mtl) {
      int mb = (wave * 4 + mtl) * 16 + qk * 4;
#pragma unroll
      for (int nt = 0; nt < 2; ++nt) {
        int code = (int)(state[nt * 16 + ln] & 7u);
        acc0[mtl][nt] = *(const f32x4*)&pre[(2 * 8 + code) * 256 + mb];
      }
    }
    gemm_pass<8>(hf, hp_s, wave, lane, acc0);
    __syncthreads();  // all rh-plane reads done
#pragma unroll
    for (int mtl = 0; mtl < 4; ++mtl) {
      int mb = (wave * 4 + mtl) * 16 + qk * 4;
      int kc = mb >> 5, hi2 = (mb >> 3) & 3, j0 = mb & 7, lp = ln + 16 * hi2;
#pragma unroll
      for (int nt = 0; nt < 2; ++nt) {
        f32x4 z = z_s[mtl][nt], ho = hold[mtl][nt], hn;
        bh4 P0, P1, P2;
#pragma unroll
        for (int j = 0; j < 4; ++j) {
          float ht = tanhf(acc0[mtl][nt][j]);
          hn[j] = (1.0f - z[j]) * ho[j] + z[j] * ht;
          unsigned short h1 = f2bf(hn[j]); float r1 = hn[j] - bf2f(h1);
          unsigned short h2 = f2bf(r1);    float r2 = r1 - bf2f(h2);
          P0[j] = (short)h1; P1[j] = (short)h2; P2[j] = (short)f2bf(r2);
        }
        hold[mtl][nt] = hn;              // persists to next step
        *(bh4*)&hp_s[HPS(0, kc, nt, lp, j0)] = P0;
        *(bh4*)&hp_s[HPS(1, kc, nt, lp, j0)] = P1;
        *(bh4*)&hp_s[HPS(2, kc, nt, lp, j0)] = P2;
      }
    }
    __syncthreads();  // h_new planes visible

    // ---- logits GEMM (waves 0-1) || gumbel t+1 (waves 2-3) ----
    if (wave < 2) {
      f32x4 lacc;
#pragma unroll
      for (int j = 0; j < 4; ++j) lacc[j] = boutL[qk * 4 + j];
#pragma unroll 1
      for (int kc = 0; kc < 8; ++kc) {
        bfrag B0 = *(const bfrag*)&hp_s[HPS(0, kc, wave, lane, 0)];
        bfrag B1 = *(const bfrag*)&hp_s[HPS(1, kc, wave, lane, 0)];
        bfrag B2 = *(const bfrag*)&hp_s[HPS(2, kc, wave, lane, 0)];
        bfrag A[3];
#pragma unroll
        for (int p = 0; p < 3; ++p)
          A[p] = *(const bfrag*)(woutf + (p * 8 + kc) * 512 + lane * 8);
        lacc = prod6(A, B0, B1, B2, lacc);
      }
      // D[m=qk*4+j][n=ln]: vocab 0..3 at qk=0, vocab 4..5 at qk=1 regs 0..1
      float l4 = __shfl(lacc[0], ln + 16, 64);
      float l5 = __shfl(lacc[1], ln + 16, 64);
      if (qk == 0) {
        const int m = wave * 16 + ln;
        const int row = b0 + m;
        unsigned st = state[m];
        if (!(st & 8u)) {
          float l[VT] = {lacc[0], lacc[1], lacc[2], lacc[3], l4, l5};
          float best = 0.f; int tok = 0;
#pragma unroll
          for (int v = 0; v < VT; ++v) {
            float val = l[v] + gmb_s[((t & 1) * 32 + m) * 6 + v];
            if (v == 0 || val > best) { best = val; tok = v; }
          }
          float lmax = l[0];
#pragma unroll
          for (int v = 1; v < VT; ++v) lmax = fmaxf(lmax, l[v]);
          float s = 0.f;
#pragma unroll
          for (int v = 0; v < VT; ++v) s += expf(l[v] - lmax);
          float lp = (l[tok] - lmax) - logf(s);
          tlp[m] += lp;
          const bool is_stop = (tok == VT - 1);
          unsigned len = ((st >> 4) & 7u) + (is_stop ? 0u : 1u);
#pragma unroll
          for (int v = 0; v < VT; ++v)
            out[(size_t)row * (TS * VT) + t * VT + v] = (v == tok) ? 1.0f : 0.0f;
          state[m] = (unsigned)tok | (is_stop ? 8u : 0u) | (len << 4);
        } else {
#pragma unroll
          for (int v = 0; v < VT; ++v)
            out[(size_t)row * (TS * VT) + t * VT + v] = 0.0f;
          state[m] = 6u | 8u | (st & 0x70u);
        }
      }
    } else if (t + 1 < TS) {
      gen_gumbel(gmb_s, t + 1, b0, wave - 2, lane, keys.a[t + 1], keys.b[t + 1]);
    }
    __syncthreads();  // state/tlp/gumbels visible for next step
  }

  if (tid < BM) {
    const int row = b0 + tid;
    out[(size_t)NB * (TS * VT) + row]      = tlp[tid];
    out[(size_t)NB * (TS * VT) + NB + row] = (float)((state[tid] >> 4) & 7u);
  }
}

extern "C" void kernel_launch(void* const* d_in, const int* in_sizes, int n_in,
                              void* d_out, int out_size, void* d_ws, size_t ws_size,
                              hipStream_t stream) {
  (void)in_sizes; (void)n_in; (void)out_size; (void)ws_size;
  const float* x          = (const float*)d_in[0];
  const float* W_enc      = (const float*)d_in[1];
  const float* b_enc      = (const float*)d_in[2];
  const float* W_embed    = (const float*)d_in[3];
  const float* b_embed    = (const float*)d_in[4];
  const float* W_z        = (const float*)d_in[5];
  const float* b_z        = (const float*)d_in[6];
  const float* W_r        = (const float*)d_in[7];
  const float* b_r        = (const float*)d_in[8];
  const float* W_h        = (const float*)d_in[9];
  const float* b_h        = (const float*)d_in[10];
  const float* W_out      = (const float*)d_in[11];
  const float* b_out      = (const float*)d_in[12];
  const float* start_embed= (const float*)d_in[13];
  float* out = (float*)d_out;

  // workspace: pre [0,24576); enc frags [24576,221184); z [221184,614400);
  // r [614400,1007616); h [1007616,1400832); wout frags [1400832,1425408)
  float* pre = (float*)d_ws;
  unsigned short* encf = (unsigned short*)((char*)d_ws + 24576);
  unsigned short* zfb  = (unsigned short*)((char*)d_ws + 221184);
  unsigned short* rfb  = (unsigned short*)((char*)d_ws + 614400);
  unsigned short* hfb  = (unsigned short*)((char*)d_ws + 1007616);
  unsigned short* wof  = (unsigned short*)((char*)d_ws + 1400832);

  pre_kernel<<<138, 256, 0, stream>>>(W_enc, W_embed, b_embed, start_embed,
                                      W_z, b_z, W_r, b_r, W_h, b_h, W_out,
                                      pre, encf, zfb, rfb, hfb, wof);

  // keys = jax.random.split(jax.random.key(42), 6), partitionable mode
  Keys K;
  for (int t = 0; t < 6; ++t) {
    uint32_t o0, o1;
    tf2x32(0u, 42u, 0u, (uint32_t)t, o0, o1);
    K.a[t] = o0; K.b[t] = o1;
  }

  main_kernel<<<NB / BM, NTH, 0, stream>>>(x, b_enc, b_out,
                                           pre, encf, zfb, rfb, hfb, wof, out, K);
}